// Round 6
// baseline (426.692 us; speedup 1.0000x reference)
//
#include <hip/hip_runtime.h>

#define NPTS 150000
#define NHEAD 5
#define KTOT 1152
#define NTILES 1172   // ceil(150000/128)
#define NBLK 586      // ceil(150000/256)
#define EPSV 1e-5f

typedef __bf16 bf16x8 __attribute__((ext_vector_type(8)));
typedef float f32x4 __attribute__((ext_vector_type(4)));
typedef unsigned short u16x8 __attribute__((ext_vector_type(8)));

// ws layout (bytes):
//   xbf      @ 0          : 150016*128*2      = 38,404,096
//   w1t      @ 38404096   : 5*128*1152*2      =  1,474,560   (pre-swizzled B^T)
//   accw     @ 39878656   : 5*150000*128*2    = 192,000,000
//     (hist @ accw+0 ; off @ accw+2,097,152 — both pre-GEMM only)
//   partials @ 231878656  : 1172*1280*4       =  6,000,640
//   stats    @ 237879296  : 1280*4            =      5,120
//   perm     @ 237884416  : 150000*4          =    600,000
#define WS_NEEDED 238484416UL

__device__ __forceinline__ unsigned short f2bf(float f) {
    unsigned int u = __float_as_uint(f);
    u += 0x7FFFu + ((u >> 16) & 1u);          // round-to-nearest-even
    return (unsigned short)(u >> 16);
}

__device__ __forceinline__ void gload16(const void* g, void* l) {
    __builtin_amdgcn_global_load_lds((const __attribute__((address_space(1))) void*)g,
                                     (__attribute__((address_space(3))) void*)l, 16, 0, 0);
}

// ---------------- pass 1: x (f32) -> bf16, plus zero pad row at index NPTS ----
__global__ void k_convert(const float* __restrict__ x, unsigned short* __restrict__ xbf) {
    const size_t i8 = (size_t)blockIdx.x * 256 + threadIdx.x;
    const size_t base = i8 * 8;
    if (base >= (size_t)(NPTS + 1) * 128) return;
    if (base < (size_t)NPTS * 128) {
        float4 v0 = *(const float4*)(x + base);
        float4 v1 = *(const float4*)(x + base + 4);
        u16x8 o;
        o[0] = f2bf(v0.x); o[1] = f2bf(v0.y); o[2] = f2bf(v0.z); o[3] = f2bf(v0.w);
        o[4] = f2bf(v1.x); o[5] = f2bf(v1.y); o[6] = f2bf(v1.z); o[7] = f2bf(v1.w);
        *(u16x8*)(xbf + base) = o;
    } else {
        u16x8 z = {0,0,0,0,0,0,0,0};
        *(u16x8*)(xbf + base) = z;
    }
}

// ---- pass 2: W1[h][k][c][d] -> w1t bf16 B^T with baked T2 swizzle ------------
__global__ void k_w1t(const float* __restrict__ W1, unsigned short* __restrict__ w1t) {
    const int idx = blockIdx.x * 256 + threadIdx.x;   // 737280 = 2880*256 exact
    const int d = idx & 127;
    const int c = (idx >> 7) & 127;
    const int hk = idx >> 14;           // h*9 + k
    const int k = hk % 9, h = hk / 9;
    const int col = h * 128 + d;
    const int p = k * 128 + c;
    const int j0 = (p >> 3) & 7;
    const int jj = j0 ^ (col & 7);
    w1t[(size_t)col * KTOT + (p & ~63) + jj * 8 + (p & 7)] = f2bf(W1[idx]);
}

// ---- sort pass A: per-block histogram of 9-bit validity patterns -------------
__global__ void k_hist(const int* __restrict__ nbr, int* __restrict__ hist) {
    __shared__ int lh[512];
    const int t = threadIdx.x, b = blockIdx.x;
    lh[t] = 0; lh[t + 256] = 0;
    __syncthreads();
    const int n = b * 256 + t;
    if (n < NPTS) {
        int pat = 0;
#pragma unroll
        for (int k = 0; k < 9; k++) pat |= (nbr[n * 9 + k] != NPTS) << k;
        atomicAdd(&lh[pat], 1);
    }
    __syncthreads();
    hist[b * 512 + t] = lh[t];
    hist[b * 512 + t + 256] = lh[t + 256];
}

// ---- sort pass B: offsets (parallel Hillis-Steele scan) -----------------------
__global__ void k_off(const int* __restrict__ hist, int* __restrict__ off) {
    __shared__ int tot[512];
    const int k = threadIdx.x;
    int s = 0;
    for (int b = 0; b < NBLK; b++) s += hist[b * 512 + k];
    tot[k] = s;
    __syncthreads();
    for (int d = 1; d < 512; d <<= 1) {
        const int v = (k >= d) ? tot[k - d] : 0;
        __syncthreads();
        tot[k] += v;
        __syncthreads();
    }
    int run = tot[k] - s;                       // exclusive prefix
    for (int b = 0; b < NBLK; b++) { off[b * 512 + k] = run; run += hist[b * 512 + k]; }
}

// ---- sort pass C: stable rank-scatter into perm ------------------------------
__global__ void k_scatter(const int* __restrict__ nbr, const int* __restrict__ off,
                          int* __restrict__ perm) {
    __shared__ int pat_s[256];
    const int t = threadIdx.x, b = blockIdx.x;
    const int n = b * 256 + t;
    int pat = -1;
    if (n < NPTS) {
        pat = 0;
#pragma unroll
        for (int k = 0; k < 9; k++) pat |= (nbr[n * 9 + k] != NPTS) << k;
    }
    pat_s[t] = pat;
    __syncthreads();
    if (n < NPTS) {
        int rank = 0;
        for (int j = 0; j < 256; j++) rank += (j < t) & (pat_s[j] == pat);
        perm[off[b * 512 + pat] + rank] = n;
    }
}

// ------- pass 3: sparse gather-GEMM, BN=160, 2 blocks/CU ----------------------
__global__ __launch_bounds__(512, 4) void k_gemm(
    const unsigned short* __restrict__ xbf,
    const unsigned short* __restrict__ w1t,
    const int* __restrict__ nbr,
    const int* __restrict__ perm,
    unsigned short* __restrict__ accw,
    float* __restrict__ partials)
{
    // A dbuf: shorts [0,16384) ; B dbuf: shorts [16384,36864)
    // epilogue aliases: C 128x168 shorts [0,21504) ; scratch floats @ short 24576 (1280 f)
    __shared__ unsigned short ABC[36864];            // 73,728 B
    __shared__ int nbr_s[9 * 128];                   // 4,608 B
    __shared__ int perm_s[128];                      // 512 B
    __shared__ int mask_s;

    const int tid = threadIdx.x;
    const int wid = tid >> 6;
    const int lane = tid & 63;
    const int bm = blockIdx.x;
    const int b2 = blockIdx.y;              // which 160-col quarter
    const int tile = (bm * 331) % NTILES;   // spread heavy tiles
    const int tile0 = tile * 128;

    if (tid == 0) mask_s = 0;
    if (tid < 128) {
        const int gr = tile0 + tid;
        perm_s[tid] = (gr < NPTS) ? perm[gr] : NPTS;
    }
    __syncthreads();
    if (tid < 128) {
        const int prow = perm_s[tid];
        int pat = 0;
#pragma unroll
        for (int k = 0; k < 9; k++) {
            const int v = (prow < NPTS) ? nbr[prow * 9 + k] : NPTS;
            nbr_s[k * 128 + tid] = v;
            pat |= (v != NPTS) << k;
        }
        if (pat) atomicOr(&mask_s, pat);
    }
    __syncthreads();
    const int mask = mask_s;                 // block-uniform (bit4 set unless all-pad)
    const int steps = 2 * __builtin_popcount(mask);

    const int RM = (wid >> 1) * 32;          // wave rows: 32
    const int CNl = (wid & 1) * 80;          // wave cols: 80
    const int lr8 = lane >> 3;
    const int jlA = (lane & 7) ^ lr8;

    f32x4 acc[2][5];
#pragma unroll
    for (int m = 0; m < 2; m++)
#pragma unroll
        for (int n = 0; n < 5; n++) acc[m][n] = f32x4{0.f, 0.f, 0.f, 0.f};

    // stage one BK=64 K-tile: 36 segments of 1 KB (A:16, B:20)
    auto stage = [&](int buf, int step) {
        const int kn = step >> 1;
        const int c0A = (step & 1) * 64 + jlA * 8;
#pragma unroll
        for (int j = 0; j < 5; ++j) {
            const int g = wid + 8 * j;               // wave-uniform
            if (g < 16) {                            // A rows g*8..g*8+7
                const int r = g * 8 + lr8;
                const int idx = nbr_s[kn * 128 + r];
                gload16(xbf + (size_t)idx * 128 + c0A, (void*)(ABC + buf * 8192 + g * 512));
            } else if (g < 36) {                     // B local cols (g-16)*8..+7
                const int lc = (g - 16) * 8 + lr8;
                gload16(w1t + (size_t)(b2 * 160 + lc) * KTOT + step * 64 + (lane & 7) * 8,
                        (void*)(ABC + 16384 + buf * 10240 + (g - 16) * 512));
            }
        }
    };

    auto compute = [&](int buf) {
        const unsigned short* Ab = ABC + buf * 8192;
        const unsigned short* Bb = ABC + 16384 + buf * 10240;
#pragma unroll
        for (int kh = 0; kh < 2; ++kh) {
            const int jj = (kh * 4 + (lane >> 4)) ^ (lane & 7);
            bf16x8 a[2];
#pragma unroll
            for (int m = 0; m < 2; m++)
                a[m] = *reinterpret_cast<const bf16x8*>(&Ab[(RM + m * 16 + (lane & 15)) * 64 + jj * 8]);
#pragma unroll
            for (int n = 0; n < 5; n++) {
                const bf16x8 b = *reinterpret_cast<const bf16x8*>(&Bb[(CNl + n * 16 + (lane & 15)) * 64 + jj * 8]);
#pragma unroll
                for (int m = 0; m < 2; m++)
                    acc[m][n] = __builtin_amdgcn_mfma_f32_16x16x32_bf16(a[m], b, acc[m][n], 0, 0, 0);
            }
        }
    };

    // walk set bits of mask: (kn,0),(kn,1),(kn',0),...
    int ckn = __builtin_ctz(mask | 16), ch = 0, rem = (mask | 16) & ((mask | 16) - 1), buf = 0;
    stage(0, ckn * 2);
    __syncthreads();
    for (int i = 0; i < steps; i++) {
        int nkn, nh, nrem;
        if (ch == 0) { nkn = ckn; nh = 1; nrem = rem; }
        else { nkn = rem ? __builtin_ctz(rem) : 0; nh = 0; nrem = rem & (rem - 1); }
        if (i + 1 < steps) stage(buf ^ 1, nkn * 2 + nh);
        compute(buf);
        __syncthreads();
        ckn = nkn; ch = nh; rem = nrem; buf ^= 1;
    }

    // ---- per-column sums/sumsq (deterministic) ----
    float* scratch = (float*)&ABC[24576];    // 4 groups x 320 floats
    const int g = wid >> 1;
    float sn[5], qn[5];
#pragma unroll
    for (int n = 0; n < 5; n++) {
        float s = 0.f, q = 0.f;
#pragma unroll
        for (int m = 0; m < 2; m++)
#pragma unroll
            for (int r = 0; r < 4; r++) { const float v = acc[m][n][r]; s += v; q += v * v; }
        s += __shfl_xor(s, 16); s += __shfl_xor(s, 32);
        q += __shfl_xor(q, 16); q += __shfl_xor(q, 32);
        sn[n] = s; qn[n] = q;
    }
    if (lane < 16) {
#pragma unroll
        for (int n = 0; n < 5; n++) {
            const int lc = CNl + n * 16 + lane;
            scratch[g * 320 + lc] = sn[n];
            scratch[g * 320 + 160 + lc] = qn[n];
        }
    }
    __syncthreads();
    if (tid < 320) {
        const int isq = (tid >= 160);
        const int lc = isq ? (tid - 160) : tid;
        const float v = scratch[isq * 160 + lc] + scratch[320 + isq * 160 + lc]
                      + scratch[640 + isq * 160 + lc] + scratch[960 + isq * 160 + lc];
        partials[(size_t)bm * 1280 + isq * 640 + b2 * 160 + lc] = v;
    }

    // ---- C store via LDS transpose (C: shorts [0,21504), disjoint from scratch) ----
    unsigned short* C = (unsigned short*)ABC;        // 128 x 168
#pragma unroll
    for (int m = 0; m < 2; m++) {
        const int row = RM + m * 16 + (lane >> 4) * 4;
#pragma unroll
        for (int n = 0; n < 5; n++) {
            const int col = CNl + n * 16 + (lane & 15);
#pragma unroll
            for (int r = 0; r < 4; r++)
                C[(row + r) * 168 + col] = f2bf(acc[m][n][r]);
        }
    }
    __syncthreads();
#pragma unroll
    for (int j = 0; j < 5; j++) {
        const int chunk = tid + 512 * j;             // 2560 chunks = 128 rows x 20
        const int row = chunk / 20, cc = chunk % 20;
        const int prow = perm_s[row];
        if (prow < NPTS) {
            const int col = b2 * 160 + cc * 8;
            const int hh = col >> 7, d = col & 127;
            *(u16x8*)(accw + ((size_t)hh * NPTS + prow) * 128 + d) =
                *(const u16x8*)&C[row * 168 + cc * 8];
        }
    }
}

// ---------------- pass 4: finalize mean/rstd over 1172 partials ----------------
__global__ void k_stats(const float* __restrict__ partials, float* __restrict__ stats) {
    __shared__ float red[256];
    const int t = threadIdx.x;
    const int c0 = blockIdx.x * 32;
    const int half = (t >> 5) & 1;
    const int l32 = t & 31;
    const int chunk = t >> 6;
    const int off = half ? (640 + c0 + l32) : (c0 + l32);
    float v = 0.f;
    for (int b = chunk; b < NTILES; b += 4) v += partials[(size_t)b * 1280 + off];
    red[t] = v;
    __syncthreads();
    if (t < 64) red[t] = red[t] + red[t + 64] + red[t + 128] + red[t + 192];
    __syncthreads();
    if (t < 32) {
        const float s = red[t], q = red[t + 32];
        const float mean = s * (1.f / NPTS);
        const float var = q * (1.f / NPTS) - mean * mean;
        const float rstd = rsqrtf(var + EPSV);
        stats[c0 + t] = mean;
        stats[640 + c0 + t] = rstd;
    }
}

// ---------------- pass 5: normalize + relu + W2 + bias + mask ------------------
__global__ void k_out(const unsigned short* __restrict__ accw,
                      const float* __restrict__ stats,
                      const float* __restrict__ gamma, const float* __restrict__ beta,
                      const float* __restrict__ W2, const float* __restrict__ b2,
                      float* __restrict__ out) {
    __shared__ float sc[128], sh[128], w2s[384], b2s[3];
    const int h = blockIdx.y;
    const int t = threadIdx.x;
    if (t < 128) {
        const float mean = stats[h * 128 + t];
        const float rstd = stats[640 + h * 128 + t];
        const float g = gamma[h * 128 + t];
        const float bb = beta[h * 128 + t];
        sc[t] = rstd * g;
        sh[t] = bb - mean * rstd * g;
        w2s[t * 3 + 0] = W2[(h * 128 + t) * 3 + 0];
        w2s[t * 3 + 1] = W2[(h * 128 + t) * 3 + 1];
        w2s[t * 3 + 2] = W2[(h * 128 + t) * 3 + 2];
    }
    if (t < 3) b2s[t] = b2[h * 3 + t];
    __syncthreads();
    const int chunk = t & 15;                 // 16-B chunk within row
    const int rloc = t >> 4;                  // 16 rows per iteration
    const int base = blockIdx.x * 128;
    const int noc = (h == 2) ? 1 : ((h == 1 || h == 4) ? 2 : 3);
#pragma unroll
    for (int it = 0; it < 8; ++it) {
        const int n = base + it * 16 + rloc;
        float o0 = 0.f, o1 = 0.f, o2 = 0.f;
        if (n < NPTS) {
            const u16x8 v = *(const u16x8*)(accw + ((size_t)h * NPTS + n) * 128 + chunk * 8);
#pragma unroll
            for (int j = 0; j < 8; j++) {
                const int c = chunk * 8 + j;
                const float a = __uint_as_float(((unsigned int)v[j]) << 16);
                const float hc = fmaxf(fmaf(a, sc[c], sh[c]), 0.f);
                o0 = fmaf(hc, w2s[c * 3 + 0], o0);
                o1 = fmaf(hc, w2s[c * 3 + 1], o1);
                o2 = fmaf(hc, w2s[c * 3 + 2], o2);
            }
        }
        o0 += __shfl_xor(o0, 1); o1 += __shfl_xor(o1, 1); o2 += __shfl_xor(o2, 1);
        o0 += __shfl_xor(o0, 2); o1 += __shfl_xor(o1, 2); o2 += __shfl_xor(o2, 2);
        o0 += __shfl_xor(o0, 4); o1 += __shfl_xor(o1, 4); o2 += __shfl_xor(o2, 4);
        o0 += __shfl_xor(o0, 8); o1 += __shfl_xor(o1, 8); o2 += __shfl_xor(o2, 8);
        if (chunk == 0 && n < NPTS) {
            const size_t ob = ((size_t)h * NPTS + n) * 3;
            out[ob + 0] = (noc > 0) ? (o0 + b2s[0]) : 0.f;
            out[ob + 1] = (noc > 1) ? (o1 + b2s[1]) : 0.f;
            out[ob + 2] = (noc > 2) ? (o2 + b2s[2]) : 0.f;
        }
    }
}

__global__ void k_sentinel(float* __restrict__ out, int n) {
    const int i = blockIdx.x * 256 + threadIdx.x;
    if (i < n) out[i] = 12345.0f;
}

extern "C" void kernel_launch(void* const* d_in, const int* in_sizes, int n_in,
                              void* d_out, int out_size, void* d_ws, size_t ws_size,
                              hipStream_t stream) {
    const float* x     = (const float*)d_in[0];
    const int*   nbr   = (const int*)d_in[1];
    const float* W1    = (const float*)d_in[2];
    const float* gamma = (const float*)d_in[3];
    const float* beta  = (const float*)d_in[4];
    const float* W2    = (const float*)d_in[5];
    const float* b2    = (const float*)d_in[6];
    float* out = (float*)d_out;

    if (ws_size < WS_NEEDED) {
        k_sentinel<<<(out_size + 255) / 256, 256, 0, stream>>>(out, out_size);
        return;
    }

    char* ws = (char*)d_ws;
    unsigned short* xbf      = (unsigned short*)(ws);
    unsigned short* w1t      = (unsigned short*)(ws + 38404096);
    unsigned short* accw     = (unsigned short*)(ws + 39878656);
    int*            hist     = (int*)(ws + 39878656);            // aliases accw (pre-GEMM)
    int*            off      = (int*)(ws + 39878656 + 2097152);  // aliases accw (pre-GEMM)
    float*          partials = (float*)(ws + 231878656);
    float*          stats    = (float*)(ws + 237879296);
    int*            perm     = (int*)(ws + 237884416);

    k_convert<<<9376, 256, 0, stream>>>(x, xbf);
    k_w1t<<<2880, 256, 0, stream>>>(W1, w1t);
    k_hist<<<NBLK, 256, 0, stream>>>(nbr, hist);
    k_off<<<1, 512, 0, stream>>>(hist, off);
    k_scatter<<<NBLK, 256, 0, stream>>>(nbr, off, perm);
    k_gemm<<<dim3(NTILES, 4), 512, 0, stream>>>(xbf, w1t, nbr, perm, accw, partials);
    k_stats<<<20, 256, 0, stream>>>(partials, stats);
    k_out<<<dim3(NTILES, 5), 256, 0, stream>>>(accw, stats, gamma, beta, W2, b2, out);
}

// Round 8
// 350.345 us; speedup vs baseline: 1.2179x; 1.2179x over previous
//
#include <hip/hip_runtime.h>

#define NPTS 150000
#define NHEAD 5
#define KTOT 1152
#define NTILES 1172   // ceil(150000/128)
#define NBLK 586      // ceil(150000/256)
#define HSTRIDE 592   // padded NBLK for hist_t rows
#define EPSV 1e-5f

typedef __bf16 bf16x8 __attribute__((ext_vector_type(8)));
typedef float f32x4 __attribute__((ext_vector_type(4)));
typedef unsigned short u16x8 __attribute__((ext_vector_type(8)));

// ws layout (bytes):
//   xbf      @ 0          : 150016*128*2      = 38,404,096
//   w1t      @ 38404096   : 5*128*1152*2      =  1,474,560   (pre-swizzled B^T)
//   accw     @ 39878656   : 5*150000*128*2    = 192,000,000
//     pre-GEMM aliases: hist_t @ accw+0 (512*592*4) ; tot @ +2,097,152 ; base @ +2,099,200
//   partials @ 231878656  : 1172*1280*4       =  6,000,640
//   stats    @ 237879296  : 1280*4            =      5,120
//   perm     @ 237884416  : 150000*4          =    600,000
#define WS_NEEDED 238484416UL

__device__ __forceinline__ unsigned short f2bf(float f) {
    unsigned int u = __float_as_uint(f);
    u += 0x7FFFu + ((u >> 16) & 1u);          // round-to-nearest-even
    return (unsigned short)(u >> 16);
}

__device__ __forceinline__ void gload16(const void* g, void* l) {
    __builtin_amdgcn_global_load_lds((const __attribute__((address_space(1))) void*)g,
                                     (__attribute__((address_space(3))) void*)l, 16, 0, 0);
}

// ---------------- pass 1: x (f32, nt) -> bf16 (cached), plus zero pad row -----
__global__ void k_convert(const float* __restrict__ x, unsigned short* __restrict__ xbf) {
    const size_t i8 = (size_t)blockIdx.x * 256 + threadIdx.x;
    const size_t base = i8 * 8;
    if (base >= (size_t)(NPTS + 1) * 128) return;
    if (base < (size_t)NPTS * 128) {
        const f32x4 v0 = __builtin_nontemporal_load((const f32x4*)(x + base));
        const f32x4 v1 = __builtin_nontemporal_load((const f32x4*)(x + base + 4));
        u16x8 o;
        o[0] = f2bf(v0[0]); o[1] = f2bf(v0[1]); o[2] = f2bf(v0[2]); o[3] = f2bf(v0[3]);
        o[4] = f2bf(v1[0]); o[5] = f2bf(v1[1]); o[6] = f2bf(v1[2]); o[7] = f2bf(v1[3]);
        *(u16x8*)(xbf + base) = o;              // keep cached: gather target
    } else {
        u16x8 z = {0,0,0,0,0,0,0,0};
        *(u16x8*)(xbf + base) = z;
    }
}

// ---- pass 2: W1[h][k][c][d] -> w1t bf16 B^T, 4-block swizzle per 32-short seg -
__global__ void k_w1t(const float* __restrict__ W1, unsigned short* __restrict__ w1t) {
    const int idx = blockIdx.x * 256 + threadIdx.x;   // 737280 = 2880*256 exact
    const int d = idx & 127;
    const int c = (idx >> 7) & 127;
    const int hk = idx >> 14;           // h*9 + k
    const int k = hk % 9, h = hk / 9;
    const int col = h * 128 + d;
    const int p = k * 128 + c;
    const int s32 = p >> 5;             // 32-short segment
    const int j0 = (p >> 3) & 3;        // 8-short block within segment
    const int jj = j0 ^ ((col >> 1) & 3);
    w1t[(size_t)col * KTOT + s32 * 32 + jj * 8 + (p & 7)] = f2bf(W1[idx]);
}

// ---- sort pass A: per-block histogram of 9-bit patterns (transposed out) -----
__global__ void k_hist(const int* __restrict__ nbr, int* __restrict__ hist_t) {
    __shared__ int lh[512];
    const int t = threadIdx.x, b = blockIdx.x;
    lh[t] = 0; lh[t + 256] = 0;
    __syncthreads();
    const int n = b * 256 + t;
    if (n < NPTS) {
        int pat = 0;
#pragma unroll
        for (int k = 0; k < 9; k++) pat |= (nbr[n * 9 + k] != NPTS) << k;
        atomicAdd(&lh[pat], 1);
    }
    __syncthreads();
    hist_t[t * HSTRIDE + b] = lh[t];
    hist_t[(t + 256) * HSTRIDE + b] = lh[t + 256];
}

// ---- sort pass B1: per-pattern exclusive scan over blocks (in-place) ---------
__global__ void k_scan1(int* __restrict__ hist_t, int* __restrict__ tot) {
    const int p = blockIdx.x;           // 512 patterns
    const int lane = threadIdx.x;       // 64
    int run = 0;
    for (int c = 0; c < 10; c++) {
        const int i = c * 64 + lane;
        const int orig = (i < NBLK) ? hist_t[p * HSTRIDE + i] : 0;
        int v = orig;
        for (int d = 1; d < 64; d <<= 1) {
            const int w = __shfl_up(v, d);
            if (lane >= d) v += w;
        }
        if (i < NBLK) hist_t[p * HSTRIDE + i] = run + v - orig;   // exclusive
        run += __shfl(v, 63);
    }
    if (lane == 0) tot[p] = run;
}

// ---- sort pass B2: exclusive scan over 512 pattern totals --------------------
__global__ void k_scan2(const int* __restrict__ tot, int* __restrict__ base) {
    __shared__ int t512[512];
    const int k = threadIdx.x;
    const int v = tot[k];
    t512[k] = v;
    __syncthreads();
    for (int d = 1; d < 512; d <<= 1) {
        const int w = (k >= d) ? t512[k - d] : 0;
        __syncthreads();
        t512[k] += w;
        __syncthreads();
    }
    base[k] = t512[k] - v;
}

// ---- sort pass C: stable rank-scatter into perm ------------------------------
__global__ void k_scatter(const int* __restrict__ nbr, const int* __restrict__ hist_t,
                          const int* __restrict__ base, int* __restrict__ perm) {
    __shared__ int pat_s[256];
    const int t = threadIdx.x, b = blockIdx.x;
    const int n = b * 256 + t;
    int pat = -1;
    if (n < NPTS) {
        pat = 0;
#pragma unroll
        for (int k = 0; k < 9; k++) pat |= (nbr[n * 9 + k] != NPTS) << k;
    }
    pat_s[t] = pat;
    __syncthreads();
    if (n < NPTS) {
        int rank = 0;
        for (int j = 0; j < 256; j++) rank += (j < t) & (pat_s[j] == pat);
        perm[base[pat] + hist_t[pat * HSTRIDE + b] + rank] = n;
    }
}

// ------- pass 3: sparse gather-GEMM, BK=32, BN=320, 2 blocks/CU ---------------
__global__ __launch_bounds__(512, 4) void k_gemm(
    const unsigned short* __restrict__ xbf,
    const unsigned short* __restrict__ w1t,
    const int* __restrict__ nbr,
    const int* __restrict__ perm,
    unsigned short* __restrict__ accw,
    float* __restrict__ partials)
{
    // A dbuf shorts [0,8192) ; B dbuf shorts [8192,28672)
    // epilogue aliases: C 128x168 shorts [0,21504) ; scratch 640 f @ short 22528
    __shared__ unsigned short ABC[28672];            // 57,344 B
    __shared__ int nbr_s[9 * 128];
    __shared__ int perm_s[128];
    __shared__ int mask_s;

    const int tid = threadIdx.x;
    const int wid = tid >> 6;
    const int lane = tid & 63;
    const int bm = blockIdx.x;
    const int b2 = blockIdx.y;              // which 320-col half
    const int tile = (bm * 331) % NTILES;   // spread heavy tiles
    const int tile0 = tile * 128;

    if (tid == 0) mask_s = 0;
    if (tid < 128) {
        const int gr = tile0 + tid;
        perm_s[tid] = (gr < NPTS) ? perm[gr] : NPTS;
    }
    __syncthreads();
    if (tid < 128) {
        const int prow = perm_s[tid];
        int pat = 0;
#pragma unroll
        for (int k = 0; k < 9; k++) {
            const int v = (prow < NPTS) ? nbr[prow * 9 + k] : NPTS;
            nbr_s[k * 128 + tid] = v;
            pat |= (v != NPTS) << k;
        }
        if (pat) atomicOr(&mask_s, pat);
    }
    __syncthreads();
    const int mask = mask_s | 16;            // block-uniform
    const int steps = 4 * __builtin_popcount(mask);

    const int RM = (wid >> 2) * 64;          // 2 row-groups of 64
    const int CNl = (wid & 3) * 80;          // 4 col-groups of 80
    const int lr16 = lane >> 2;              // staging: 16 rows/segment
    const int lb = lane & 3;                 // staging: 4 blocks/row
    const int jswS = (lb ^ ((lr16 >> 1) & 3)) * 8;   // source swizzle for A

    f32x4 acc[4][5];
#pragma unroll
    for (int m = 0; m < 4; m++)
#pragma unroll
        for (int n = 0; n < 5; n++) acc[m][n] = f32x4{0.f, 0.f, 0.f, 0.f};

    // stage one BK=32 K-slab: A 8 segs + B 20 segs of 1 KB
    auto stage = [&](int buf, int kn, int q) {
#pragma unroll
        for (int j = 0; j < 4; ++j) {
            const int g = wid + 8 * j;               // wave-uniform
            if (g < 8) {                             // A rows g*16..+15
                const int r = g * 16 + lr16;
                const int idx = nbr_s[kn * 128 + r];
                gload16(xbf + (size_t)idx * 128 + q * 32 + jswS,
                        (void*)(ABC + buf * 4096 + g * 512));
            } else if (g < 28) {                     // B cols (g-8)*16..+15
                const int gb = g - 8;
                const int lc = gb * 16 + lr16;
                gload16(w1t + (size_t)(b2 * 320 + lc) * KTOT + (kn * 4 + q) * 32 + lb * 8,
                        (void*)(ABC + 8192 + buf * 10240 + gb * 512));
            }
        }
    };

    const int rlo = lane & 15;
    const int jsw = (((lane >> 4) ^ ((rlo >> 1) & 3))) * 8;  // read swizzle

    auto compute = [&](int buf) {
        const unsigned short* Ab = ABC + buf * 4096;
        const unsigned short* Bb = ABC + 8192 + buf * 10240;
        bf16x8 a[4];
#pragma unroll
        for (int m = 0; m < 4; m++)
            a[m] = *reinterpret_cast<const bf16x8*>(&Ab[(RM + m * 16 + rlo) * 32 + jsw]);
#pragma unroll
        for (int n = 0; n < 5; n++) {
            const bf16x8 b = *reinterpret_cast<const bf16x8*>(&Bb[(CNl + n * 16 + rlo) * 32 + jsw]);
#pragma unroll
            for (int m = 0; m < 4; m++)
                acc[m][n] = __builtin_amdgcn_mfma_f32_16x16x32_bf16(a[m], b, acc[m][n], 0, 0, 0);
        }
    };

    // walk (kn, q=0..3) over set bits of mask
    int ckn = __builtin_ctz(mask), cq = 0, rem = mask & (mask - 1), buf = 0;
    stage(0, ckn, 0);
    __syncthreads();
    for (int i = 0; i < steps; i++) {
        int nkn, nq, nrem;
        if (cq < 3) { nkn = ckn; nq = cq + 1; nrem = rem; }
        else { nkn = rem ? __builtin_ctz(rem) : 0; nq = 0; nrem = rem & (rem - 1); }
        if (i + 1 < steps) stage(buf ^ 1, nkn, nq);
        compute(buf);
        __syncthreads();
        ckn = nkn; cq = nq; rem = nrem; buf ^= 1;
    }

    // ---- per-column sums/sumsq (deterministic) ----
    float* scratch = (float*)&ABC[22528];    // 2 groups x 320 floats
    const int g = wid >> 2;
    float sn[5], qn[5];
#pragma unroll
    for (int n = 0; n < 5; n++) {
        float s = 0.f, q = 0.f;
#pragma unroll
        for (int m = 0; m < 4; m++)
#pragma unroll
            for (int r = 0; r < 4; r++) { const float v = acc[m][n][r]; s += v; q += v * v; }
        s += __shfl_xor(s, 16); s += __shfl_xor(s, 32);
        q += __shfl_xor(q, 16); q += __shfl_xor(q, 32);
        sn[n] = s; qn[n] = q;
    }
    __syncthreads();
    if (lane < 16 && g == 0) {
#pragma unroll
        for (int n = 0; n < 5; n++) {
            const int lc = CNl + n * 16 + lane;
            scratch[lc] = sn[n]; scratch[320 + lc] = qn[n];
        }
    }
    __syncthreads();
    if (lane < 16 && g == 1) {
#pragma unroll
        for (int n = 0; n < 5; n++) {
            const int lc = CNl + n * 16 + lane;
            scratch[lc] += sn[n]; scratch[320 + lc] += qn[n];
        }
    }
    __syncthreads();
    for (int t = tid; t < 640; t += 512) {               // FIX: loop, not if(tid<640)
        const int isq = (t >= 320);
        const int lc = isq ? (t - 320) : t;
        partials[(size_t)bm * 1280 + isq * 640 + b2 * 320 + lc] = scratch[isq * 320 + lc];
    }

    // ---- C store via LDS transpose, two half-col passes (stride 168) ----
    unsigned short* C = (unsigned short*)ABC;            // 128 x 168 per pass
#pragma unroll
    for (int p = 0; p < 2; ++p) {
        __syncthreads();
        if (((wid >> 1) & 1) == p) {                     // waves owning cols p*160..p*160+159
            const int colbase = CNl - p * 160;           // 0 or 80
#pragma unroll
            for (int m = 0; m < 4; m++) {
                const int row = RM + m * 16 + (lane >> 4) * 4;
#pragma unroll
                for (int n = 0; n < 5; n++) {
                    const int col = colbase + n * 16 + rlo;
#pragma unroll
                    for (int r = 0; r < 4; r++)
                        C[(row + r) * 168 + col] = f2bf(acc[m][n][r]);
                }
            }
        }
        __syncthreads();
#pragma unroll
        for (int j = 0; j < 5; j++) {
            const int chunk = tid + 512 * j;             // 2560 = 128 rows x 20 chunks
            const int row = chunk / 20, cc = chunk % 20;
            const int prow = perm_s[row];
            if (prow < NPTS) {
                const int col = b2 * 320 + p * 160 + cc * 8;
                const int hh = col >> 7, d = col & 127;
                __builtin_nontemporal_store(*(const u16x8*)&C[row * 168 + cc * 8],
                    (u16x8*)(accw + ((size_t)hh * NPTS + prow) * 128 + d));
            }
        }
    }
}

// ---------------- pass 4: finalize mean/rstd over 1172 partials ----------------
__global__ void k_stats(const float* __restrict__ partials, float* __restrict__ stats) {
    __shared__ float red[256];
    const int t = threadIdx.x;
    const int c0 = blockIdx.x * 32;
    const int half = (t >> 5) & 1;
    const int l32 = t & 31;
    const int chunk = t >> 6;
    const int off = half ? (640 + c0 + l32) : (c0 + l32);
    float v = 0.f;
    for (int b = chunk; b < NTILES; b += 4) v += partials[(size_t)b * 1280 + off];
    red[t] = v;
    __syncthreads();
    if (t < 64) red[t] = red[t] + red[t + 64] + red[t + 128] + red[t + 192];
    __syncthreads();
    if (t < 32) {
        const float s = red[t], q = red[t + 32];
        const float mean = s * (1.f / NPTS);
        const float var = q * (1.f / NPTS) - mean * mean;
        const float rstd = rsqrtf(var + EPSV);
        stats[c0 + t] = mean;
        stats[640 + c0 + t] = rstd;
    }
}

// ---------------- pass 5: normalize + relu + W2 + bias + mask (nt I/O) --------
__global__ void k_out(const unsigned short* __restrict__ accw,
                      const float* __restrict__ stats,
                      const float* __restrict__ gamma, const float* __restrict__ beta,
                      const float* __restrict__ W2, const float* __restrict__ b2,
                      float* __restrict__ out) {
    __shared__ float sc[128], sh[128], w2s[384], b2s[3];
    const int h = blockIdx.y;
    const int t = threadIdx.x;
    if (t < 128) {
        const float mean = stats[h * 128 + t];
        const float rstd = stats[640 + h * 128 + t];
        const float g = gamma[h * 128 + t];
        const float bb = beta[h * 128 + t];
        sc[t] = rstd * g;
        sh[t] = bb - mean * rstd * g;
        w2s[t * 3 + 0] = W2[(h * 128 + t) * 3 + 0];
        w2s[t * 3 + 1] = W2[(h * 128 + t) * 3 + 1];
        w2s[t * 3 + 2] = W2[(h * 128 + t) * 3 + 2];
    }
    if (t < 3) b2s[t] = b2[h * 3 + t];
    __syncthreads();
    const int chunk = t & 15;
    const int rloc = t >> 4;
    const int base = blockIdx.x * 128;
    const int noc = (h == 2) ? 1 : ((h == 1 || h == 4) ? 2 : 3);
#pragma unroll
    for (int it = 0; it < 8; ++it) {
        const int n = base + it * 16 + rloc;
        float o0 = 0.f, o1 = 0.f, o2 = 0.f;
        if (n < NPTS) {
            const u16x8 v = __builtin_nontemporal_load(
                (const u16x8*)(accw + ((size_t)h * NPTS + n) * 128 + chunk * 8));
#pragma unroll
            for (int j = 0; j < 8; j++) {
                const int c = chunk * 8 + j;
                const float a = __uint_as_float(((unsigned int)v[j]) << 16);
                const float hc = fmaxf(fmaf(a, sc[c], sh[c]), 0.f);
                o0 = fmaf(hc, w2s[c * 3 + 0], o0);
                o1 = fmaf(hc, w2s[c * 3 + 1], o1);
                o2 = fmaf(hc, w2s[c * 3 + 2], o2);
            }
        }
        o0 += __shfl_xor(o0, 1); o1 += __shfl_xor(o1, 1); o2 += __shfl_xor(o2, 1);
        o0 += __shfl_xor(o0, 2); o1 += __shfl_xor(o1, 2); o2 += __shfl_xor(o2, 2);
        o0 += __shfl_xor(o0, 4); o1 += __shfl_xor(o1, 4); o2 += __shfl_xor(o2, 4);
        o0 += __shfl_xor(o0, 8); o1 += __shfl_xor(o1, 8); o2 += __shfl_xor(o2, 8);
        if (chunk == 0 && n < NPTS) {
            const size_t ob = ((size_t)h * NPTS + n) * 3;
            __builtin_nontemporal_store((noc > 0) ? (o0 + b2s[0]) : 0.f, out + ob + 0);
            __builtin_nontemporal_store((noc > 1) ? (o1 + b2s[1]) : 0.f, out + ob + 1);
            __builtin_nontemporal_store((noc > 2) ? (o2 + b2s[2]) : 0.f, out + ob + 2);
        }
    }
}

__global__ void k_sentinel(float* __restrict__ out, int n) {
    const int i = blockIdx.x * 256 + threadIdx.x;
    if (i < n) out[i] = 12345.0f;
}

extern "C" void kernel_launch(void* const* d_in, const int* in_sizes, int n_in,
                              void* d_out, int out_size, void* d_ws, size_t ws_size,
                              hipStream_t stream) {
    const float* x     = (const float*)d_in[0];
    const int*   nbr   = (const int*)d_in[1];
    const float* W1    = (const float*)d_in[2];
    const float* gamma = (const float*)d_in[3];
    const float* beta  = (const float*)d_in[4];
    const float* W2    = (const float*)d_in[5];
    const float* b2    = (const float*)d_in[6];
    float* out = (float*)d_out;

    if (ws_size < WS_NEEDED) {
        k_sentinel<<<(out_size + 255) / 256, 256, 0, stream>>>(out, out_size);
        return;
    }

    char* ws = (char*)d_ws;
    unsigned short* xbf      = (unsigned short*)(ws);
    unsigned short* w1t      = (unsigned short*)(ws + 38404096);
    unsigned short* accw     = (unsigned short*)(ws + 39878656);
    int*            hist_t   = (int*)(ws + 39878656);            // aliases accw (pre-GEMM)
    int*            tot      = (int*)(ws + 39878656 + 2097152);
    int*            base     = (int*)(ws + 39878656 + 2099200);
    float*          partials = (float*)(ws + 231878656);
    float*          stats    = (float*)(ws + 237879296);
    int*            perm     = (int*)(ws + 237884416);

    k_convert<<<9376, 256, 0, stream>>>(x, xbf);
    k_w1t<<<2880, 256, 0, stream>>>(W1, w1t);
    k_hist<<<NBLK, 256, 0, stream>>>(nbr, hist_t);
    k_scan1<<<512, 64, 0, stream>>>(hist_t, tot);
    k_scan2<<<1, 512, 0, stream>>>(tot, base);
    k_scatter<<<NBLK, 256, 0, stream>>>(nbr, hist_t, base, perm);
    k_gemm<<<dim3(NTILES, 2), 512, 0, stream>>>(xbf, w1t, nbr, perm, accw, partials);
    k_stats<<<20, 256, 0, stream>>>(partials, stats);
    k_out<<<dim3(NTILES, 5), 256, 0, stream>>>(accw, stats, gamma, beta, W2, b2, out);
}